// Round 2
// baseline (821.327 us; speedup 1.0000x reference)
//
#include <hip/hip_runtime.h>
#include <hip/hip_bf16.h>
#include <stdint.h>

#define TOK 8192
#define DD 1024
#define FF 4096
#define EE 8
#define BM 128
#define BN 128
#define BK 64
#define MT_MAX 72  // max Σ_e ceil(cnt_e/128)

typedef __attribute__((ext_vector_type(8))) short bf16x8;
typedef __attribute__((ext_vector_type(4))) float f32x4;

// ---- workspace layout (bytes) ----
#define WS_SEL    0u                       // int[8192]
#define WS_CNT    32768u                   // int[8]
#define WS_CUR    (32768u + 64u)           // int[8]
#define WS_TSTART (32768u + 128u)          // int[9]
#define WS_ZSUM   (32768u + 192u)          // float
#define WS_PERM   33024u                   // int[9216] = 72*128
#define WS_XB     131072u                  // bf16[8192*1024]  (16 MB)
#define WS_H      (131072u + 16777216u)    // bf16[9216*4096]  (75.5 MB)

__device__ __forceinline__ unsigned short f2bf(float f) {
  unsigned int u = __builtin_bit_cast(unsigned int, f);
  u = (u + 0x7FFFu + ((u >> 16) & 1u)) >> 16;
  return (unsigned short)u;
}

__device__ __forceinline__ void async_copy16(const void* g, void* l) {
  __builtin_amdgcn_global_load_lds(
      (const __attribute__((address_space(1))) unsigned int*)g,
      (__attribute__((address_space(3))) unsigned int*)l, 16, 0, 0);
}

// ---------------- router: logits (f64 acc), argmax, z-loss, x -> bf16 ----------------
__global__ __launch_bounds__(256) void k_router(const float* __restrict__ x,
                                                const float* __restrict__ gw,
                                                uint8_t* __restrict__ ws) {
  const int wv = threadIdx.x >> 6, l = threadIdx.x & 63;
  const int t = (int)blockIdx.x * 4 + wv;
  int* sel = (int*)(ws + WS_SEL);
  int* cnt = (int*)(ws + WS_CNT);
  float* zsum = (float*)(ws + WS_ZSUM);
  unsigned short* xb = (unsigned short*)(ws + WS_XB);
  const float4* xr = (const float4*)(x + (size_t)t * DD);
  // f64 accumulation: argmax flip risk vs np reference drops ~20x (top-2 gap
  // of 8 Gaussians has O(1) density at 0; f32 tree-sum error ~2e-5 over 8192
  // tokens => ~20% chance of a misroute => absmax 3.x fail)
  double acc[EE];
#pragma unroll
  for (int e = 0; e < EE; ++e) acc[e] = 0.0;
#pragma unroll
  for (int i = 0; i < 4; ++i) {
    const int idx = l + i * 64;
    const float4 v = xr[idx];
    ushort4 b;
    b.x = f2bf(v.x); b.y = f2bf(v.y); b.z = f2bf(v.z); b.w = f2bf(v.w);
    *(ushort4*)(xb + (size_t)t * DD + (size_t)idx * 4) = b;
#pragma unroll
    for (int e = 0; e < EE; ++e) {
      const float4 g = ((const float4*)(gw + (size_t)e * DD))[idx];
      acc[e] += (double)v.x * g.x + (double)v.y * g.y +
                (double)v.z * g.z + (double)v.w * g.w;
    }
  }
#pragma unroll
  for (int e = 0; e < EE; ++e) {
#pragma unroll
    for (int s = 32; s > 0; s >>= 1) acc[e] += __shfl_xor(acc[e], s, 64);
  }
  if (l == 0) {
    double m = acc[0]; int am = 0;
#pragma unroll
    for (int e = 1; e < EE; ++e) if (acc[e] > m) { m = acc[e]; am = e; }
    float se = 0.f;
#pragma unroll
    for (int e = 0; e < EE; ++e) se += __expf((float)(acc[e] - m));
    const float lse = (float)m + __logf(se);
    sel[t] = am;
    atomicAdd(cnt + am, 1);
    atomicAdd(zsum, lse * lse);
  }
}

// ---------------- finalize: segment scan + scalar losses ----------------
__global__ void k_finalize(uint8_t* __restrict__ ws, float* __restrict__ out) {
  if (threadIdx.x != 0 || blockIdx.x != 0) return;
  int* cnt = (int*)(ws + WS_CNT);
  int* cur = (int*)(ws + WS_CUR);
  int* ts = (int*)(ws + WS_TSTART);
  int tiles = 0, s = 0;
  for (int e = 0; e < EE; ++e) {
    ts[e] = tiles;
    cur[e] = tiles * BM;
    tiles += (cnt[e] + BM - 1) / BM;
    s += cnt[e];
  }
  ts[EE] = tiles;
  const float zs = *(float*)(ws + WS_ZSUM);
  out[(size_t)TOK * DD] = (float)EE * ((float)s / (float)TOK);   // aux_loss (== 8.0)
  out[(size_t)TOK * DD + 1] = zs / (float)TOK;                   // z_loss
}

// ---------------- scatter: build permutation ----------------
__global__ __launch_bounds__(256) void k_scatter(uint8_t* __restrict__ ws) {
  const int t = (int)blockIdx.x * 256 + threadIdx.x;
  if (t >= TOK) return;
  const int e = ((const int*)(ws + WS_SEL))[t];
  const int pos = atomicAdd((int*)(ws + WS_CUR) + e, 1);
  ((int*)(ws + WS_PERM))[pos] = t;
}

// ---------------- grouped GEMM (C = A * W^T + bias), 128x128 tile ----------------
// GEMM1: A = Xb (indirect rows via perm), gelu -> H (bf16)
// GEMM2: A = H (direct rows), scatter f32 rows to out via perm
template <int K, int NTOT, bool DOGELU, bool INDIRECT>
__global__ __launch_bounds__(256) void k_gemm(const unsigned short* __restrict__ A,
                                              const float* __restrict__ W,
                                              const float* __restrict__ bias,
                                              uint8_t* __restrict__ ws,
                                              float* __restrict__ out) {
  const int* ts = (const int*)(ws + WS_TSTART);
  const int* perm = (const int*)(ws + WS_PERM);
  unsigned short* H = (unsigned short*)(ws + WS_H);

  // bijective XCD-chunked swizzle, m-fast ordering (weight-column L2 reuse)
  const int MT = (int)gridDim.x;
  const int nblk = MT * (int)gridDim.y;
  const int orig = (int)blockIdx.y * MT + (int)blockIdx.x;
  const int q = nblk >> 3, r = nblk & 7;
  const int xcd = orig & 7, b8 = orig >> 3;
  const int wg = (xcd < r ? xcd * (q + 1) : r * (q + 1) + (xcd - r) * q) + b8;
  const int mt = wg % MT, nt = wg / MT;

  const int total = ts[EE];
  if (mt >= total) return;
  int e = 0;
#pragma unroll
  for (int i = 1; i < EE; ++i) if (mt >= ts[i]) e = i;

  const int m0 = mt * BM, n0 = nt * BN;
  const float* Wb = W + (size_t)e * NTOT * K;
  const float* bs = bias + (size_t)e * NTOT;

  __shared__ __align__(16) unsigned short As[BM * BK];
  __shared__ __align__(16) unsigned short Bs[BN * BK];

  const int tid = threadIdx.x, wv = tid >> 6, l = tid & 63;
  const int wr = wv >> 1, wc = wv & 1;

  f32x4 acc[4][4];
#pragma unroll
  for (int m = 0; m < 4; ++m)
#pragma unroll
    for (int n = 0; n < 4; ++n) acc[m][n] = f32x4{0.f, 0.f, 0.f, 0.f};

  int arow[4];
#pragma unroll
  for (int j = 0; j < 4; ++j) {
    const int row = (tid + j * 256) >> 3;
    if (INDIRECT) {
      const int tk = perm[m0 + row];
      arow[j] = tk < 0 ? 0 : tk;   // padded rows: token 0 (finite garbage, masked at store)
    } else {
      arow[j] = m0 + row;
    }
  }

  for (int k0 = 0; k0 < K; k0 += BK) {
    // A: global_load_lds width 16, pre-swizzled source (rule #21: linear LDS
    // dest + inverse-swizzled global src + swizzled read = consistent)
#pragma unroll
    for (int j = 0; j < 4; ++j) {
      const int p = tid + j * 256;
      const int row = p >> 3, pc = p & 7;
      const int lc = pc ^ (row & 7);
      const unsigned short* src = A + (size_t)arow[j] * K + k0 + lc * 8;
      async_copy16(src, (char*)As + (size_t)(j * 256 + wv * 64) * 16);
    }
    // B: f32 -> bf16 reg-staged, swizzled ds_write
#pragma unroll
    for (int i = 0; i < 8; ++i) {
      const int c = tid + i * 256;
      const int row = c >> 4, cc = c & 15;
      const float4 v = *(const float4*)(Wb + (size_t)(n0 + row) * K + k0 + cc * 4);
      uint2 u;
      u.x = (unsigned)f2bf(v.x) | ((unsigned)f2bf(v.y) << 16);
      u.y = (unsigned)f2bf(v.z) | ((unsigned)f2bf(v.w) << 16);
      const int phys = row * 128 + (((cc >> 1) ^ (row & 7)) << 4) + ((cc & 1) << 3);
      *(uint2*)((char*)Bs + phys) = u;
    }
    __syncthreads();
#pragma unroll
    for (int kk = 0; kk < 2; ++kk) {
      const int ch = kk * 4 + (l >> 4);  // 16B chunk index of this lane's k-slice
      bf16x8 af[4], bfr[4];
#pragma unroll
      for (int m = 0; m < 4; ++m) {
        const int row = wr * 64 + m * 16 + (l & 15);
        af[m] = *(const bf16x8*)((const char*)As + row * 128 + ((ch ^ (row & 7)) << 4));
      }
#pragma unroll
      for (int n = 0; n < 4; ++n) {
        const int row = wc * 64 + n * 16 + (l & 15);
        bfr[n] = *(const bf16x8*)((const char*)Bs + row * 128 + ((ch ^ (row & 7)) << 4));
      }
#pragma unroll
      for (int m = 0; m < 4; ++m)
#pragma unroll
        for (int n = 0; n < 4; ++n)
          acc[m][n] = __builtin_amdgcn_mfma_f32_16x16x32_bf16(af[m], bfr[n], acc[m][n], 0, 0, 0);
    }
    __syncthreads();
  }

  // epilogue: C layout col = lane&15, row = (lane>>4)*4 + reg   [m89-verified]
  const int cl = l & 15, rg = l >> 4;
#pragma unroll
  for (int n = 0; n < 4; ++n) {
    const int col = n0 + wc * 64 + n * 16 + cl;
    const float bv = bs[col];
#pragma unroll
    for (int m = 0; m < 4; ++m) {
      const int rbase = m0 + wr * 64 + m * 16 + rg * 4;
#pragma unroll
      for (int qq = 0; qq < 4; ++qq) {
        const int rr = rbase + qq;
        float v = acc[m][n][qq] + bv;
        if (DOGELU) {
          const float u0 = 0.7978845608028654f * (v + 0.044715f * v * v * v);
          const float th = 1.f - 2.f / (__expf(2.f * u0) + 1.f);  // tanh
          v = 0.5f * v * (1.f + th);
          H[(size_t)rr * FF + col] = f2bf(v);
        } else {
          const int tk = perm[rr];
          if (tk >= 0) out[(size_t)tk * DD + col] = v;
        }
      }
    }
  }
}

extern "C" void kernel_launch(void* const* d_in, const int* in_sizes, int n_in,
                              void* d_out, int out_size, void* d_ws, size_t ws_size,
                              hipStream_t stream) {
  const float* x = (const float*)d_in[0];
  const float* gw = (const float*)d_in[1];
  const float* w1 = (const float*)d_in[2];
  const float* b1 = (const float*)d_in[3];
  const float* w2 = (const float*)d_in[4];
  const float* b2 = (const float*)d_in[5];
  float* out = (float*)d_out;
  uint8_t* ws = (uint8_t*)d_ws;

  hipMemsetAsync(ws + WS_CNT, 0, 256, stream);                    // counts/cursors/zsum
  hipMemsetAsync(ws + WS_PERM, 0xFF, MT_MAX * BM * 4, stream);    // perm = -1

  k_router<<<TOK / 4, 256, 0, stream>>>(x, gw, ws);
  k_finalize<<<1, 64, 0, stream>>>(ws, out);
  k_scatter<<<TOK / 256, 256, 0, stream>>>(ws);

  const unsigned short* Xb = (const unsigned short*)(ws + WS_XB);
  const unsigned short* Hb = (const unsigned short*)(ws + WS_H);
  k_gemm<DD, FF, true, true><<<dim3(MT_MAX, FF / BN), 256, 0, stream>>>(Xb, w1, b1, ws, out);
  k_gemm<FF, DD, false, false><<<dim3(MT_MAX, DD / BN), 256, 0, stream>>>(Hb, w2, b2, ws, out);
}